// Round 14
// baseline (123.737 us; speedup 1.0000x reference)
//
#include <hip/hip_runtime.h>
#include <hip/hip_bf16.h>

typedef unsigned short u16;
typedef unsigned int u32;
typedef __attribute__((ext_vector_type(8))) short short8;   // 8 bf16 (4 VGPRs)
typedef __attribute__((ext_vector_type(4))) float f32x4;    // MFMA accumulator
typedef __attribute__((ext_vector_type(4))) u16 u16x4;

static constexpr int Bb = 512, Tt = 256, Cc = 768, Hh = 64;

__device__ __forceinline__ u16 f2bf(float f) {
    __hip_bfloat16 h = __float2bfloat16(f);   // RNE
    union { __hip_bfloat16 h; u16 u; } v; v.h = h;
    return v.u;
}

__device__ __forceinline__ void gll16(const u16* g, u16* l) {
    __builtin_amdgcn_global_load_lds(
        (const __attribute__((address_space(1))) u32*)g,
        (__attribute__((address_space(3))) u32*)l, 16, 0, 0);
}

// ---------------------------------------------------------------------------
// Kernel 0 (r12-proven): Wq|Wk|Wv -> 32-k sub-chunk fragment-major bf16 image.
// Sub-chunk s = k>>5 is 12288 B: frag nt = n>>4 (1 KB each); lane lf =
// (n&15) + ((k>>3)&3)*16; elem e = k&7.  Staged linearly with global_load_lds;
// read as 16 B/lane at nt*1024 + l*16.
// ---------------------------------------------------------------------------
__global__ void wt_kernel(const float* __restrict__ Wq, const float* __restrict__ Wk,
                          const float* __restrict__ Wv, u16* __restrict__ Wf) {
    int idx = blockIdx.x * 256 + threadIdx.x;          // 192*768
    int n = idx / Cc, k = idx % Cc;
    const float* W = (n < 64) ? Wq : (n < 128) ? Wk : Wv;
    float val = W[k * Hh + (n & 63)];
    int nt = n >> 4, fr = n & 15;
    int j = k >> 6, s = (k >> 5) & 1;
    int lf = fr + (((k >> 3) & 3) << 4), e = k & 7;
    Wf[(size_t)j * 12288 + s * 6144 + nt * 512 + lf * 8 + e] = f2bf(val);
}

// ---------------------------------------------------------------------------
// Fused kernel: one block per batch, 512 thr = 8 waves.
// Phase 1 (QKV GEMM, 24 x 32-k steps): x staged in 128-k EVENTS (S_0..S_5),
//   each read as TWO 128-row halves where every load instruction covers
//   512 B CONTIGUOUS per x-row (2x DRAM row dwell vs champion's 256 B — the
//   single variable under test).  XS = 2 x 64 KB (each holds 128 k bf16,
//   swizzled); one register set, load at chunk c -> LDS-write at c+1 (full
//   chunk of latency cover).  W: 32-k sub-chunks dbuf 2x12 KB via
//   global_load_lds (r12 scheme).  Plain __syncthreads per step (proven).
//   Ledger: S_j halves H0/H1 written at chunks 2j-2 / 2j-1; buffer's previous
//   tenant S_{j-2} last read at chunk 2j-3 -> barrier-ordered, no race.
// Epilogue + Phase 2: byte-identical to the r7/r13 champion (passing).
// LDS (155648 B): p1: XS [0,131072) | WS [131072,155648)
//                 p2: KT [0,32768) | VT [32768,65536) | QB [65536,98304)
//                     P  [98304,118784)
// ---------------------------------------------------------------------------
__global__ __launch_bounds__(512, 2) void fused_kernel(
        const float* __restrict__ x, const u16* __restrict__ Wf,
        const int* __restrict__ pad, float* __restrict__ out) {
    __shared__ u16 smem[77824];   // 155648 B
    char* smB = (char*)smem;

    const int tid = threadIdx.x;
    const int w = tid >> 6, l = tid & 63;
    const int lrow = l & 15, lgrp = l >> 4;
    const int b = blockIdx.x;
    const int cswz = (lrow & 7) << 4;
    const int tt0 = w, tt1 = 15 - w;          // owned query-row tiles

    float4 xr[8];
    f32x4 acc[2][12];
#pragma unroll
    for (int i = 0; i < 2; ++i)
#pragma unroll
        for (int j = 0; j < 12; ++j) acc[i][j] = (f32x4)0.f;

// Load half h_ (rows [h_*128, +128)) of staging event j_ (k [j_*128,+128)).
// Granule g = tid + r*512: row g>>5, 16-B piece g&31 -> per wave-instr the
// 64 lanes cover 2 rows x 512 B CONTIGUOUS each.
#define XLOAD(j_, h_)                                                          \
    _Pragma("unroll")                                                          \
    for (int r = 0; r < 8; ++r) {                                              \
        int g = tid + r * 512;                                                 \
        xr[r] = *(const float4*)(x + ((size_t)b * Tt + (h_) * 128 + (g >> 5)) * Cc \
                                 + (j_) * 128 + (g & 31) * 4);                 \
    }

// cvt + write to XS buf nb_: row-swizzled [256 rows][256 B] bf16 image.
#define XWRITE(h_, nb_)                                                        \
    _Pragma("unroll")                                                          \
    for (int r = 0; r < 8; ++r) {                                              \
        int g = tid + r * 512;                                                 \
        int row = (h_) * 128 + (g >> 5);                                       \
        int kb = (g & 31) * 8;                                                 \
        u16x4 pk;                                                              \
        pk[0] = f2bf(xr[r].x); pk[1] = f2bf(xr[r].y);                          \
        pk[2] = f2bf(xr[r].z); pk[3] = f2bf(xr[r].w);                          \
        *(u16x4*)(smB + (nb_) * 65536 + row * 256 + (kb ^ ((row & 7) << 4))) = pk; \
    }

// Stage W sub-chunk s_ (12288 B) into WS buf s_&1.
#define WSTAGE(s_)                                                             \
    {                                                                          \
        u16* wl_ = smem + 65536 + ((s_) & 1) * 6144;                           \
        const u16* wg_ = Wf + (size_t)(s_) * 6144;                             \
        gll16(wg_ + tid * 8, wl_ + tid * 8);                                   \
        if (tid < 256) gll16(wg_ + 4096 + tid * 8, wl_ + 4096 + tid * 8);      \
    }

#define COMPUTE(sg_)                                                           \
    {                                                                          \
        const char* xb = smB + (((sg_) >> 2) & 1) * 65536;                     \
        const char* wb = smB + 131072 + ((sg_) & 1) * 12288;                   \
        short8 bfr[12], af[2];                                                 \
        _Pragma("unroll")                                                      \
        for (int nt = 0; nt < 12; ++nt)                                        \
            bfr[nt] = *(const short8*)(wb + nt * 1024 + l * 16);               \
        const int kof = ((sg_) & 3) * 64;                                      \
        af[0] = *(const short8*)(xb + (tt0 * 16 + lrow) * 256 +                \
                                 ((kof + lgrp * 16) ^ cswz));                  \
        af[1] = *(const short8*)(xb + (tt1 * 16 + lrow) * 256 +                \
                                 ((kof + lgrp * 16) ^ cswz));                  \
        _Pragma("unroll")                                                      \
        for (int mt = 0; mt < 2; ++mt)                                         \
            _Pragma("unroll")                                                  \
            for (int nt = 0; nt < 12; ++nt)                                    \
                acc[mt][nt] = __builtin_amdgcn_mfma_f32_16x16x32_bf16(         \
                    af[mt], bfr[nt], acc[mt][nt], 0, 0, 0);                    \
    }

    // ---- Phase 1 prologue: S0 fully staged, S1H0 loaded, W0 staged ----
    XLOAD(0, 0); XWRITE(0, 0);
    XLOAD(0, 1); XWRITE(1, 0);
    XLOAD(1, 0);                 // S1H0, written at chunk 0
    WSTAGE(0);
    __syncthreads();

    // ---- Main loop: 24 x 32-k steps ----
#pragma unroll 1
    for (int sg = 0; sg < 24; ++sg) {
        if (sg < 23) { WSTAGE(sg + 1); }
        if ((sg & 1) == 0) {
            const int c = sg >> 1;
            // write the half loaded last chunk, then load the next half
            const int jw = (c & 1) ? (c + 1) / 2 : c / 2 + 1;
            const int hw = (c & 1) ? 1 : 0;
            if (jw <= 5) { XWRITE(hw, jw & 1); }
            const int jl = (c & 1) ? (c + 3) / 2 : c / 2 + 1;
            const int hl = (c & 1) ? 0 : 1;
            if (jl <= 5) { XLOAD(jl, hl); }
        }
        COMPUTE(sg);
        __syncthreads();
    }
#undef XLOAD
#undef XWRITE
#undef WSTAGE
#undef COMPUTE

    // ---- Epilogue: acc -> KT / VT / QB (champion, unchanged) ----
#pragma unroll
    for (int mrep = 0; mrep < 2; ++mrep) {
        const int tt = (mrep == 0) ? tt0 : tt1;
        const int s0 = tt * 16;
#pragma unroll
        for (int nt = 0; nt < 12; ++nt) {
            f32x4 a = acc[mrep][nt];
            if (nt < 4) {                       // Q -> QB [256][64]
                int h = nt * 16 + lrow;
#pragma unroll
                for (int r = 0; r < 4; ++r) {
                    int row = s0 + lgrp * 4 + r;
                    *(u16*)(smB + 65536 + ((row * 128 + h * 2) ^ ((row & 7) << 4))) = f2bf(a[r]);
                }
            } else if (nt < 8) {                // K -> KT [256][64]
                int h = (nt - 4) * 16 + lrow;
#pragma unroll
                for (int r = 0; r < 4; ++r) {
                    int s = s0 + lgrp * 4 + r;
                    *(u16*)(smB + ((s * 128 + h * 2) ^ ((s & 7) << 4))) = f2bf(a[r]);
                }
            } else {                            // V -> VT [64][256]
                int h = (nt - 8) * 16 + lrow;
                int s = s0 + lgrp * 4;
                u16x4 pk;
                pk[0] = f2bf(a[0]); pk[1] = f2bf(a[1]);
                pk[2] = f2bf(a[2]); pk[3] = f2bf(a[3]);
                *(u16x4*)(smB + 32768 + h * 512 + ((s * 2) ^ ((h & 15) << 4))) = pk;
            }
        }
    }
    __syncthreads();

    // Q fragment readback
    short8 qfr[2][2];
#pragma unroll
    for (int mt = 0; mt < 2; ++mt) {
        const int tt = (mt == 0) ? tt0 : tt1;
#pragma unroll
        for (int kk = 0; kk < 2; ++kk)
            qfr[mt][kk] = *(const short8*)(smB + 65536 +
                (((tt * 16 + lrow) * 128 + kk * 64 + lgrp * 16) ^ cswz));
    }
    __syncthreads();    // all qfr reads done before P overwrites QB space

    // ---- Phase 2: causal attention (per-wave, no barriers) ----
    char* pbase = smB + 98304 + w * 2560;
#pragma unroll
    for (int mt = 0; mt < 2; ++mt) {
        const int tt = (mt == 0) ? tt0 : tt1;
        const int i0 = tt * 16;

        f32x4 sreg[16];
#pragma unroll
        for (int t = 0; t < 16; ++t) {
            if (t <= tt) {
                short8 k0 = *(const short8*)(smB +
                    (((t * 16 + lrow) * 128 + lgrp * 16) ^ cswz));
                short8 k1 = *(const short8*)(smB +
                    (((t * 16 + lrow) * 128 + 64 + lgrp * 16) ^ cswz));
                f32x4 s = (f32x4)0.f;
                s = __builtin_amdgcn_mfma_f32_16x16x32_bf16(qfr[mt][0], k0, s, 0, 0, 0);
                s = __builtin_amdgcn_mfma_f32_16x16x32_bf16(qfr[mt][1], k1, s, 0, 0, 0);
                if (t == tt) {
#pragma unroll
                    for (int r = 0; r < 4; ++r) {
                        int i = i0 + lgrp * 4 + r;
                        int sidx = t * 16 + lrow;
                        sreg[t][r] = (sidx <= i) ? s[r] * 0.125f : -1e30f;
                    }
                } else {
#pragma unroll
                    for (int r = 0; r < 4; ++r) sreg[t][r] = s[r] * 0.125f;
                }
            }
        }

        f32x4 mx = (f32x4)(-1e30f);
#pragma unroll
        for (int t = 0; t < 16; ++t)
            if (t <= tt)
#pragma unroll
                for (int r = 0; r < 4; ++r) mx[r] = fmaxf(mx[r], sreg[t][r]);
#pragma unroll
        for (int m = 1; m <= 8; m <<= 1)
#pragma unroll
            for (int r = 0; r < 4; ++r) mx[r] = fmaxf(mx[r], __shfl_xor(mx[r], m, 64));

        f32x4 sm = (f32x4)0.f;
#pragma unroll
        for (int t = 0; t < 16; ++t)
            if (t <= tt)
#pragma unroll
                for (int r = 0; r < 4; ++r) {
                    float p = __expf(sreg[t][r] - mx[r]);
                    sreg[t][r] = p;
                    sm[r] += p;
                }
#pragma unroll
        for (int m = 1; m <= 8; m <<= 1)
#pragma unroll
            for (int r = 0; r < 4; ++r) sm[r] += __shfl_xor(sm[r], m, 64);

        float inv[4];
#pragma unroll
        for (int r = 0; r < 4; ++r) {
            int i = i0 + lgrp * 4 + r;
            inv[r] = (pad[b * Tt + i] != 0) ? (1.0f / sm[r]) : 0.0f;
        }

        f32x4 o[4];
#pragma unroll
        for (int ht = 0; ht < 4; ++ht) o[ht] = (f32x4)0.f;
#pragma unroll
        for (int ks = 0; ks < 8; ++ks) {
            if (2 * ks <= tt) {
                char* pb = pbase + (ks & 1) * 1280;
#pragma unroll
                for (int r = 0; r < 4; ++r) {
                    int prow = lgrp * 4 + r;
                    *(u16*)(pb + prow * 80 + lrow * 2) = f2bf(sreg[2 * ks][r]);
                    u16 pv2 = (2 * ks + 1 <= tt) ? f2bf(sreg[2 * ks + 1][r]) : (u16)0;
                    *(u16*)(pb + prow * 80 + 32 + lrow * 2) = pv2;
                }
                short8 pa = *(const short8*)(pb + lrow * 80 + lgrp * 16);
#pragma unroll
                for (int ht = 0; ht < 4; ++ht) {
                    short8 vfr = *(const short8*)(smB + 32768 + (ht * 16 + lrow) * 512 +
                        ((ks * 64 + lgrp * 16) ^ (lrow << 4)));
                    o[ht] = __builtin_amdgcn_mfma_f32_16x16x32_bf16(pa, vfr, o[ht], 0, 0, 0);
                }
            }
        }

        float* outp = out + ((size_t)b * Tt + i0) * Hh;
#pragma unroll
        for (int r = 0; r < 4; ++r)
#pragma unroll
            for (int ht = 0; ht < 4; ++ht)
                outp[(lgrp * 4 + r) * Hh + ht * 16 + lrow] = o[ht][r] * inv[r];
    }
}

// ---------------------------------------------------------------------------
extern "C" void kernel_launch(void* const* d_in, const int* in_sizes, int n_in,
                              void* d_out, int out_size, void* d_ws, size_t ws_size,
                              hipStream_t stream) {
    const float* x  = (const float*)d_in[0];
    const float* Wq = (const float*)d_in[1];
    const float* Wk = (const float*)d_in[2];
    const float* Wv = (const float*)d_in[3];
    const int* pad  = (const int*)d_in[4];
    float* out = (float*)d_out;

    u16* Wf = (u16*)d_ws;    // 294912 B

    wt_kernel<<<576, 256, 0, stream>>>(Wq, Wk, Wv, Wf);
    fused_kernel<<<Bb, 512, 0, stream>>>(x, Wf, pad, out);
}